// Round 7
// baseline (8975.703 us; speedup 1.0000x reference)
//
#include <hip/hip_runtime.h>
#include <hip/hip_bf16.h>
#include <math.h>

// ---------------- problem dims ----------------
#define BB      32
#define LTOK    196
#define DMODEL  384
#define DINNER  768
#define DSTATE  16
#define DTRANK  24
#define DCONV   4
#define PROJW   64                    // padded x-proj width (56 -> 64)
#define NTOK    (BB*LTOK)             // 6272 = 49*128
#define NCLS    1000
#define EPS     1e-5f
#define NCH     14                    // scan chunks
#define CL      14                    // tokens per chunk (14*14 = 196)

typedef __attribute__((ext_vector_type(8))) short short8v;
typedef __attribute__((ext_vector_type(4))) float f32x4;

static __device__ __forceinline__ ushort f2bf(float f) {
    unsigned u = __float_as_uint(f);
    unsigned r = (u + 0x7fffu + ((u >> 16) & 1u)) >> 16;   // RNE
    return (ushort)r;
}
static __device__ __forceinline__ float bf2f(ushort h) {
    return __uint_as_float(((unsigned)h) << 16);
}

// ---------------- fp32 -> bf16 cast (grid-stride, vectorized) ----------------
__global__ void cast_bf16_kernel(const float* __restrict__ src,
                                 ushort* __restrict__ dst, int n4)
{
    int stride = gridDim.x * blockDim.x;
    for (int i = blockIdx.x * blockDim.x + threadIdx.x; i < n4; i += stride) {
        float4 v = ((const float4*)src)[i];
        ushort4 o;
        o.x = f2bf(v.x); o.y = f2bf(v.y); o.z = f2bf(v.z); o.w = f2bf(v.w);
        ((ushort4*)dst)[i] = o;
    }
}

// ---- W_xp [24,56,768] -> bf16 [24,64,768] (zero-padded rows) ----
__global__ void pad_wxp_kernel(const float* __restrict__ src, ushort* __restrict__ dst)
{
    int idx = blockIdx.x * 256 + threadIdx.x;
    if (idx >= 24 * 64 * 768) return;
    int c = idx % 768;
    int r = (idx / 768) & 63;
    int l = idx / (64 * 768);
    dst[idx] = (r < 56) ? f2bf(src[((size_t)l * 56 + r) * 768 + c]) : (ushort)0;
}

// ---- W_dt [24,768,24] -> bf16 [24,768,32] (zero-padded cols) ----
__global__ void pad_wdt_kernel(const float* __restrict__ src, ushort* __restrict__ dst)
{
    int idx = blockIdx.x * 256 + threadIdx.x;
    if (idx >= 24 * 768 * 32) return;
    int c = idx & 31;
    int r = (idx / 32) % 768;
    int l = idx / (768 * 32);
    dst[idx] = (c < 24) ? f2bf(src[((size_t)l * 768 + r) * 24 + c]) : (ushort)0;
}

// ---------------- bf16 MFMA GEMM: C[M,N] = A[M,K]*B[N,K]^T --------------------
// M%BM==0, N%BN==0, K%32==0. 4 waves in 2x2; wave tile (BM/2)x(BN/2).
// mode 0: Cf fp32 (+bias +rowbias +act)
// mode 1: Cbf bf16 (ld = N)
// mode 2: Cf fp32 (ld = N) AND dt-pad bf16 [M,32] (col<24 = value, 24..31 = 0)
template<int BM, int BN>
__global__ __launch_bounds__(256) void gemm_mfma(
    const ushort* __restrict__ A,
    const ushort* __restrict__ B,
    float* __restrict__ Cf, ushort* __restrict__ Cbf,
    int N, int K,
    const float* __restrict__ bias,
    const float* __restrict__ rowbias,
    int act, int mode)
{
    constexpr int MI = BM / 32;      // frags per wave in M
    constexpr int NI = BN / 32;
    __shared__ __align__(16) ushort As[BM * 40];   // 80B rows
    __shared__ __align__(16) ushort Bs[BN * 40];
    const int t    = threadIdx.x;
    const int lane = t & 63;
    const int wave = t >> 6;
    const int wr   = wave >> 1;
    const int wc   = wave & 1;
    const int lr   = lane & 15;
    const int lk   = lane >> 4;
    const int bm   = blockIdx.x * BM;
    const int bn   = blockIdx.y * BN;

    f32x4 acc[MI][NI];
    #pragma unroll
    for (int i = 0; i < MI; i++)
        #pragma unroll
        for (int j = 0; j < NI; j++) acc[i][j] = (f32x4){0.f, 0.f, 0.f, 0.f};

    for (int k0 = 0; k0 < K; k0 += 32) {
        #pragma unroll
        for (int i = 0; i < BM / 64; i++) {
            int c = t + i * 256;
            int row = c >> 2, kc = (c & 3) * 8;
            *(int4*)&As[row * 40 + kc] = *(const int4*)&A[(size_t)(bm + row) * K + k0 + kc];
        }
        #pragma unroll
        for (int i = 0; i < BN / 64; i++) {
            int c = t + i * 256;
            int row = c >> 2, kc = (c & 3) * 8;
            *(int4*)&Bs[row * 40 + kc] = *(const int4*)&B[(size_t)(bn + row) * K + k0 + kc];
        }
        __syncthreads();
        short8v af[MI], bfr[NI];
        #pragma unroll
        for (int mi = 0; mi < MI; mi++)
            af[mi] = *(short8v*)&As[(wr * (BM / 2) + mi * 16 + lr) * 40 + lk * 8];
        #pragma unroll
        for (int ni = 0; ni < NI; ni++)
            bfr[ni] = *(short8v*)&Bs[(wc * (BN / 2) + ni * 16 + lr) * 40 + lk * 8];
        #pragma unroll
        for (int mi = 0; mi < MI; mi++)
            #pragma unroll
            for (int ni = 0; ni < NI; ni++)
                acc[mi][ni] = __builtin_amdgcn_mfma_f32_16x16x32_bf16(
                    af[mi], bfr[ni], acc[mi][ni], 0, 0, 0);
        __syncthreads();
    }

    #pragma unroll
    for (int mi = 0; mi < MI; mi++) {
        #pragma unroll
        for (int ni = 0; ni < NI; ni++) {
            int col = bn + wc * (BN / 2) + ni * 16 + lr;
            float bv = bias ? bias[col] : 0.f;
            #pragma unroll
            for (int j = 0; j < 4; j++) {
                int row = bm + wr * (BM / 2) + mi * 16 + lk * 4 + j;
                float v = acc[mi][ni][j] + bv;
                if (rowbias) v += rowbias[(size_t)(row % LTOK) * N + col];
                if (act == 1) v = (v > 20.f) ? v : logf(1.f + __expf(v));
                if (mode == 0) {
                    Cf[(size_t)row * N + col] = v;
                } else if (mode == 1) {
                    Cbf[(size_t)row * N + col] = f2bf(v);
                } else {
                    Cf[(size_t)row * N + col] = v;
                    if (col < 32)
                        Cbf[(size_t)row * 32 + col] = (col < DTRANK) ? f2bf(v) : (ushort)0;
                }
            }
        }
    }
}

// ---------------- im2col for patch embed (writes bf16) ----------------
__global__ void im2col_kernel(const float* __restrict__ x, ushort* __restrict__ col)
{
    int idx = blockIdx.x * 256 + threadIdx.x;        // over NTOK*768
    if (idx >= NTOK * 768) return;
    int k = idx % 768;
    int m = idx / 768;
    int b = m / LTOK, l = m % LTOK;
    int ph = l / 14, pw = l % 14;
    int c = k / 256, rr = k % 256;
    int i = rr / 16, j = rr % 16;
    col[idx] = f2bf(x[(((size_t)b * 3 + c) * 224 + ph * 16 + i) * 224 + pw * 16 + j]);
}

// ---------------- fused residual-add + LayerNorm (fp32 + bf16 outputs) -------
__global__ __launch_bounds__(64) void add_ln_kernel(
    float* __restrict__ residual, const float* __restrict__ hidden,
    const float* __restrict__ w, const float* __restrict__ b,
    float* __restrict__ xln, ushort* __restrict__ xln_bf)
{
    const int token = blockIdx.x;
    const int lane  = threadIdx.x;
    const size_t base = (size_t)token * DMODEL;
    float v[6];
    float sum = 0.f;
    #pragma unroll
    for (int i = 0; i < 6; i++) {
        int d = lane + i * 64;
        float r = residual[base + d] + hidden[base + d];
        v[i] = r;
        sum += r;
    }
    #pragma unroll
    for (int off = 32; off > 0; off >>= 1) sum += __shfl_xor(sum, off);
    float mu = sum * (1.f / DMODEL);
    float var = 0.f;
    #pragma unroll
    for (int i = 0; i < 6; i++) { float c = v[i] - mu; var += c * c; }
    #pragma unroll
    for (int off = 32; off > 0; off >>= 1) var += __shfl_xor(var, off);
    var *= (1.f / DMODEL);
    float rstd = rsqrtf(var + EPS);
    #pragma unroll
    for (int i = 0; i < 6; i++) {
        int d = lane + i * 64;
        residual[base + d] = v[i];
        float o = (v[i] - mu) * rstd * w[d] + b[d];
        xln[base + d]    = o;
        xln_bf[base + d] = f2bf(o);
    }
}

// ---------------- depthwise causal conv (k=4) + SiLU (bf16 in, dual out) -----
__global__ __launch_bounds__(256) void conv_silu_kernel(
    const ushort* __restrict__ xz,     // [NTOK,1536] bf16; xc = cols 0..767
    const float* __restrict__ cw,      // [768,4]
    const float* __restrict__ cb,      // [768]
    float* __restrict__ out,           // [NTOK,768] fp32 (scan u)
    ushort* __restrict__ out_bf)       // [NTOK,768] bf16 (x-proj A)
{
    int idx = blockIdx.x * 256 + threadIdx.x;
    if (idx >= NTOK * DINNER) return;
    int e = idx % DINNER;
    int m = idx / DINNER;
    int b = m / LTOK, tpos = m % LTOK;
    float4 w4 = ((const float4*)cw)[e];
    float wv[4] = {w4.x, w4.y, w4.z, w4.w};
    float acc = cb[e];
    #pragma unroll
    for (int tau = 0; tau < DCONV; tau++) {
        int l = tpos - (DCONV - 1) + tau;
        if (l >= 0)
            acc += wv[tau] * bf2f(xz[((size_t)(b * LTOK + l)) * (2 * DINNER) + e]);
    }
    float s = acc / (1.f + __expf(-acc));
    out[idx]    = s;
    out_bf[idx] = f2bf(s);
}

// ---------------- chunked parallel selective scan ----------------------------
// Grid: (BB, DINNER/64). Block: (64 channels, NCH chunks) = 896 threads.
// Phase A: per-chunk local scan from h=0; record S=sum(dt), h_loc[16] -> LDS.
// Phase B: each thread folds preceding chunks' (S, h_loc) -> its true h_in.
//          exp(dt1*A)*exp(dt2*A) = exp((dt1+dt2)*A) makes chunk transitions
//          representable by the scalar S.
// Phase C: re-run own chunk from h_in; emit y = (h.C + u*Dp)*silu(z) as bf16.
__global__ __launch_bounds__(896) void scan_chunked_kernel(
    const float* __restrict__ delta,   // [NTOK,768]
    const float* __restrict__ u,       // [NTOK,768]
    const float* __restrict__ proj,    // [NTOK,64]  (dt|B|C, padded)
    const ushort* __restrict__ xz,     // [NTOK,1536] bf16 (z = cols 768..1535)
    const float* __restrict__ A_log,   // [768,16]
    const float* __restrict__ Dp,      // [768]
    ushort* __restrict__ y)            // [NTOK,768] bf16
{
    __shared__ float S_l[NCH][64];
    __shared__ float hl[NCH][DSTATE][64];   // [chunk][state][channel]
    const int b  = blockIdx.x;
    const int dl = threadIdx.x;             // 0..63
    const int c  = threadIdx.y;             // 0..NCH-1 (== wave id)
    const int d  = blockIdx.y * 64 + dl;

    float Arow[DSTATE];
    #pragma unroll
    for (int n = 0; n < DSTATE; n++) Arow[n] = -__expf(A_log[(size_t)d * DSTATE + n]);

    const size_t row0 = (size_t)b * LTOK + c * CL;
    float dts[CL], us[CL];
    float h[DSTATE];
    #pragma unroll
    for (int n = 0; n < DSTATE; n++) h[n] = 0.f;
    float S = 0.f;

    // ---- Phase A: local scan, h_in = 0 ----
    for (int i = 0; i < CL; i++) {
        const size_t row = row0 + i;
        const float dt = delta[row * DINNER + d];
        const float ut = u[row * DINNER + d];
        dts[i] = dt; us[i] = ut;
        S += dt;
        const float du = dt * ut;
        const float4* prB = (const float4*)(proj + row * PROJW + DTRANK);
        #pragma unroll
        for (int q = 0; q < 4; q++) {
            float4 b4 = prB[q];
            h[q*4+0] = __expf(dt * Arow[q*4+0]) * h[q*4+0] + du * b4.x;
            h[q*4+1] = __expf(dt * Arow[q*4+1]) * h[q*4+1] + du * b4.y;
            h[q*4+2] = __expf(dt * Arow[q*4+2]) * h[q*4+2] + du * b4.z;
            h[q*4+3] = __expf(dt * Arow[q*4+3]) * h[q*4+3] + du * b4.w;
        }
    }
    S_l[c][dl] = S;
    #pragma unroll
    for (int n = 0; n < DSTATE; n++) hl[c][n][dl] = h[n];
    __syncthreads();

    // ---- Phase B: fold preceding chunks (trip count uniform per wave) ----
    float hin[DSTATE];
    #pragma unroll
    for (int n = 0; n < DSTATE; n++) hin[n] = 0.f;
    for (int cp = 0; cp < c; cp++) {
        const float Sp = S_l[cp][dl];
        #pragma unroll
        for (int n = 0; n < DSTATE; n++)
            hin[n] = __expf(Sp * Arow[n]) * hin[n] + hl[cp][n][dl];
    }

    // ---- Phase C: re-run own chunk from true h_in, emit outputs ----
    const float ddp = Dp[d];
    for (int i = 0; i < CL; i++) {
        const size_t row = row0 + i;
        const float dt = dts[i], ut = us[i];
        const float du = dt * ut;
        const float4* prB = (const float4*)(proj + row * PROJW + DTRANK);
        const float4* prC = (const float4*)(proj + row * PROJW + DTRANK + DSTATE);
        float acc = 0.f;
        #pragma unroll
        for (int q = 0; q < 4; q++) {
            float4 b4 = prB[q];
            float4 c4 = prC[q];
            hin[q*4+0] = __expf(dt * Arow[q*4+0]) * hin[q*4+0] + du * b4.x;
            hin[q*4+1] = __expf(dt * Arow[q*4+1]) * hin[q*4+1] + du * b4.y;
            hin[q*4+2] = __expf(dt * Arow[q*4+2]) * hin[q*4+2] + du * b4.z;
            hin[q*4+3] = __expf(dt * Arow[q*4+3]) * hin[q*4+3] + du * b4.w;
            acc += hin[q*4+0] * c4.x + hin[q*4+1] * c4.y +
                   hin[q*4+2] * c4.z + hin[q*4+3] * c4.w;
        }
        float zz = bf2f(xz[row * (2 * DINNER) + DINNER + d]);
        float g  = zz / (1.f + __expf(-zz));
        y[row * DINNER + d] = f2bf((acc + ut * ddp) * g);
    }
}

// ---------------- mean pool over tokens ----------------
__global__ __launch_bounds__(256) void pool_kernel(const float* __restrict__ xln,
                                                   float* __restrict__ pooled)
{
    int idx = blockIdx.x * 256 + threadIdx.x;   // 32*384
    if (idx >= BB * DMODEL) return;
    int b = idx / DMODEL, d = idx % DMODEL;
    float s = 0.f;
    for (int l = 0; l < LTOK; l++) s += xln[((size_t)b * LTOK + l) * DMODEL + d];
    pooled[idx] = s * (1.f / LTOK);
}

// ---------------- classifier head ----------------
__global__ __launch_bounds__(256) void head_kernel(const float* __restrict__ pooled,
                                                   const float* __restrict__ hw,
                                                   const float* __restrict__ hb,
                                                   float* __restrict__ out)
{
    int idx = blockIdx.x * 256 + threadIdx.x;   // 32*1000
    if (idx >= BB * NCLS) return;
    int b = idx / NCLS, n = idx % NCLS;
    float s = hb[n];
    const float* p = pooled + (size_t)b * DMODEL;
    const float* w = hw + (size_t)n * DMODEL;
    for (int k = 0; k < DMODEL; k++) s += p[k] * w[k];
    out[idx] = s;
}

// ---------------- launcher ----------------
extern "C" void kernel_launch(void* const* d_in, const int* in_sizes, int n_in,
                              void* d_out, int out_size, void* d_ws, size_t ws_size,
                              hipStream_t stream)
{
    const float* x       = (const float*)d_in[0];
    const float* patch_w = (const float*)d_in[1];
    const float* patch_b = (const float*)d_in[2];
    const float* pos     = (const float*)d_in[3];
    const float* W_in    = (const float*)d_in[4];
    const float* conv_w  = (const float*)d_in[5];
    const float* conv_b  = (const float*)d_in[6];
    const float* W_xp    = (const float*)d_in[7];
    const float* W_dt    = (const float*)d_in[8];
    const float* b_dt    = (const float*)d_in[9];
    const float* A_log   = (const float*)d_in[10];
    const float* D_p     = (const float*)d_in[11];
    const float* W_out   = (const float*)d_in[12];
    const float* ln_w    = (const float*)d_in[13];
    const float* ln_b    = (const float*)d_in[14];
    const float* normf_w = (const float*)d_in[15];
    const float* normf_b = (const float*)d_in[16];
    const float* head_w  = (const float*)d_in[17];
    const float* head_b  = (const float*)d_in[18];
    float* out = (float*)d_out;

    // ---- fp32 workspace ----
    float* wsf = (float*)d_ws;
    size_t off = 0;
    float* xcv    = wsf + off; off += (size_t)NTOK * DINNER;
    float* proj   = wsf + off; off += (size_t)NTOK * PROJW;
    float* delta  = wsf + off; off += (size_t)NTOK * DINNER;
    float* resid  = wsf + off; off += (size_t)NTOK * DMODEL;
    float* hid    = wsf + off; off += (size_t)NTOK * DMODEL;
    float* xln    = wsf + off; off += (size_t)NTOK * DMODEL;
    float* pooled = wsf + off; off += (size_t)BB * DMODEL;
    // ---- bf16 workspace ----
    ushort* wsu = (ushort*)(wsf + off);
    size_t uoff = 0;
    ushort* Win_bf    = wsu + uoff; uoff += (size_t)24 * 1536 * DMODEL;
    ushort* Wout_bf   = wsu + uoff; uoff += (size_t)24 * DMODEL * DINNER;
    ushort* patchw_bf = wsu + uoff; uoff += (size_t)DMODEL * 768;
    ushort* Wxp_bf    = wsu + uoff; uoff += (size_t)24 * 64 * DINNER;
    ushort* Wdt_bf    = wsu + uoff; uoff += (size_t)24 * DINNER * 32;
    ushort* xln_bf    = wsu + uoff; uoff += (size_t)NTOK * DMODEL;
    ushort* xz_bf     = wsu + uoff; uoff += (size_t)NTOK * 1536;
    ushort* xcv_bf    = wsu + uoff; uoff += (size_t)NTOK * DINNER;
    ushort* dtpad_bf  = wsu + uoff; uoff += (size_t)NTOK * 32;
    ushort* y_bf      = wsu + uoff; uoff += (size_t)NTOK * DINNER;
    ushort* col_bf    = y_bf;   // patch GEMM consumes before scan ever writes

    // ---- weight casts / pads (graph-safe, every call) ----
    cast_bf16_kernel<<<2048, 256, 0, stream>>>(W_in,    Win_bf,    24 * 1536 * DMODEL / 4);
    cast_bf16_kernel<<<2048, 256, 0, stream>>>(W_out,   Wout_bf,   24 * DMODEL * DINNER / 4);
    cast_bf16_kernel<<<256,  256, 0, stream>>>(patch_w, patchw_bf, DMODEL * 768 / 4);
    pad_wxp_kernel<<<(24 * 64 * 768 + 255) / 256, 256, 0, stream>>>(W_xp, Wxp_bf);
    pad_wdt_kernel<<<(24 * 768 * 32 + 255) / 256, 256, 0, stream>>>(W_dt, Wdt_bf);

    hipMemsetAsync(resid, 0, (size_t)NTOK * DMODEL * sizeof(float), stream);

    // patch embed: im2col(bf16) + MFMA GEMM (bias + pos fused)
    im2col_kernel<<<(NTOK * 768 + 255) / 256, 256, 0, stream>>>(x, col_bf);
    gemm_mfma<128,128><<<dim3(NTOK / 128, DMODEL / 128), 256, 0, stream>>>(
        col_bf, patchw_bf, hid, nullptr, DMODEL, 768, patch_b, pos, 0, 0);

    for (int l = 0; l < 24; l++) {
        add_ln_kernel<<<NTOK, 64, 0, stream>>>(resid, hid,
                                               ln_w + (size_t)l * DMODEL,
                                               ln_b + (size_t)l * DMODEL, xln, xln_bf);
        // in-projection -> xz bf16: [6272,384] x [1536,384]^T
        gemm_mfma<128,128><<<dim3(NTOK / 128, 1536 / 128), 256, 0, stream>>>(
            xln_bf, Win_bf + (size_t)l * 1536 * DMODEL, nullptr, xz_bf,
            1536, DMODEL, nullptr, nullptr, 0, 1);
        conv_silu_kernel<<<(NTOK * DINNER + 255) / 256, 256, 0, stream>>>(
            xz_bf, conv_w + (size_t)l * DINNER * DCONV, conv_b + (size_t)l * DINNER,
            xcv, xcv_bf);
        // x-proj -> proj fp32 [6272,64] + dtpad bf16 [6272,32]
        gemm_mfma<64,64><<<dim3(NTOK / 64, 1), 256, 0, stream>>>(
            xcv_bf, Wxp_bf + (size_t)l * 64 * DINNER, proj, dtpad_bf,
            64, DINNER, nullptr, nullptr, 0, 2);
        // dt-proj + softplus -> delta fp32: [6272,32] x [768,32]^T
        gemm_mfma<128,128><<<dim3(NTOK / 128, DINNER / 128), 256, 0, stream>>>(
            dtpad_bf, Wdt_bf + (size_t)l * DINNER * 32, delta, nullptr,
            DINNER, 32, b_dt + (size_t)l * DINNER, nullptr, 1, 0);
        // chunked parallel scan
        scan_chunked_kernel<<<dim3(BB, DINNER / 64), dim3(64, NCH), 0, stream>>>(
            delta, xcv, proj, xz_bf,
            A_log + (size_t)l * DINNER * DSTATE, D_p + (size_t)l * DINNER, y_bf);
        // out-projection: [6272,768] x [384,768]^T -> hid fp32
        gemm_mfma<128,128><<<dim3(NTOK / 128, DMODEL / 128), 256, 0, stream>>>(
            y_bf, Wout_bf + (size_t)l * DMODEL * DINNER, hid, nullptr,
            DMODEL, DINNER, nullptr, nullptr, 0, 0);
    }

    add_ln_kernel<<<NTOK, 64, 0, stream>>>(resid, hid, normf_w, normf_b, xln, xln_bf);
    pool_kernel<<<(BB * DMODEL + 255) / 256, 256, 0, stream>>>(xln, pooled);
    head_kernel<<<(BB * NCLS + 255) / 256, 256, 0, stream>>>(pooled, head_w, head_b, out);
}

// Round 11
// 4897.684 us; speedup vs baseline: 1.8326x; 1.8326x over previous
//
#include <hip/hip_runtime.h>
#include <hip/hip_bf16.h>
#include <math.h>

// ---------------- problem dims ----------------
#define BB      32
#define LTOK    196
#define DMODEL  384
#define DINNER  768
#define DSTATE  16
#define DTRANK  24
#define DCONV   4
#define PROJW   64                    // padded x-proj width (56 -> 64)
#define NTOK    (BB*LTOK)             // 6272 = 49*128
#define NCLS    1000
#define EPS     1e-5f
#define NCH     14                    // scan chunks
#define CL      14                    // tokens per chunk (14*14 = 196)
#define SCH     32                    // scan channels per block

typedef __attribute__((ext_vector_type(8))) short short8v;
typedef __attribute__((ext_vector_type(4))) float f32x4;

static __device__ __forceinline__ ushort f2bf(float f) {
    unsigned u = __float_as_uint(f);
    unsigned r = (u + 0x7fffu + ((u >> 16) & 1u)) >> 16;   // RNE
    return (ushort)r;
}
static __device__ __forceinline__ float bf2f(ushort h) {
    return __uint_as_float(((unsigned)h) << 16);
}

// ---------------- fp32 -> bf16 cast (grid-stride, vectorized) ----------------
__global__ void cast_bf16_kernel(const float* __restrict__ src,
                                 ushort* __restrict__ dst, int n4)
{
    int stride = gridDim.x * blockDim.x;
    for (int i = blockIdx.x * blockDim.x + threadIdx.x; i < n4; i += stride) {
        float4 v = ((const float4*)src)[i];
        ushort4 o;
        o.x = f2bf(v.x); o.y = f2bf(v.y); o.z = f2bf(v.z); o.w = f2bf(v.w);
        ((ushort4*)dst)[i] = o;
    }
}

// ---- W_xp [24,56,768] -> bf16 [24,64,768] (zero-padded rows) ----
__global__ void pad_wxp_kernel(const float* __restrict__ src, ushort* __restrict__ dst)
{
    int idx = blockIdx.x * 256 + threadIdx.x;
    if (idx >= 24 * 64 * 768) return;
    int c = idx % 768;
    int r = (idx / 768) & 63;
    int l = idx / (64 * 768);
    dst[idx] = (r < 56) ? f2bf(src[((size_t)l * 56 + r) * 768 + c]) : (ushort)0;
}

// ---- W_dt [24,768,24] -> bf16 [24,768,32] (zero-padded cols) ----
__global__ void pad_wdt_kernel(const float* __restrict__ src, ushort* __restrict__ dst)
{
    int idx = blockIdx.x * 256 + threadIdx.x;
    if (idx >= 24 * 768 * 32) return;
    int c = idx & 31;
    int r = (idx / 32) % 768;
    int l = idx / (768 * 32);
    dst[idx] = (c < 24) ? f2bf(src[((size_t)l * 768 + r) * 24 + c]) : (ushort)0;
}

// ---------------- bf16 MFMA GEMM: C[M,N] = A[M,K]*B[N,K]^T --------------------
// M%BM==0, N%BN==0, K%32==0. 4 waves in 2x2; wave tile (BM/2)x(BN/2).
// mode 0: Cf fp32 (+bias +rowbias +act)
// mode 1: Cbf bf16 (ld = N)
// mode 2: Cf fp32 (ld = N) AND dt-pad bf16 [M,32] (col<24 = value, 24..31 = 0)
template<int BM, int BN>
__global__ __launch_bounds__(256) void gemm_mfma(
    const ushort* __restrict__ A,
    const ushort* __restrict__ B,
    float* __restrict__ Cf, ushort* __restrict__ Cbf,
    int N, int K,
    const float* __restrict__ bias,
    const float* __restrict__ rowbias,
    int act, int mode)
{
    constexpr int MI = BM / 32;      // frags per wave in M
    constexpr int NI = BN / 32;
    __shared__ __align__(16) ushort As[BM * 40];   // 80B rows
    __shared__ __align__(16) ushort Bs[BN * 40];
    const int t    = threadIdx.x;
    const int lane = t & 63;
    const int wave = t >> 6;
    const int wr   = wave >> 1;
    const int wc   = wave & 1;
    const int lr   = lane & 15;
    const int lk   = lane >> 4;
    const int bm   = blockIdx.x * BM;
    const int bn   = blockIdx.y * BN;

    f32x4 acc[MI][NI];
    #pragma unroll
    for (int i = 0; i < MI; i++)
        #pragma unroll
        for (int j = 0; j < NI; j++) acc[i][j] = (f32x4){0.f, 0.f, 0.f, 0.f};

    for (int k0 = 0; k0 < K; k0 += 32) {
        #pragma unroll
        for (int i = 0; i < BM / 64; i++) {
            int c = t + i * 256;
            int row = c >> 2, kc = (c & 3) * 8;
            *(int4*)&As[row * 40 + kc] = *(const int4*)&A[(size_t)(bm + row) * K + k0 + kc];
        }
        #pragma unroll
        for (int i = 0; i < BN / 64; i++) {
            int c = t + i * 256;
            int row = c >> 2, kc = (c & 3) * 8;
            *(int4*)&Bs[row * 40 + kc] = *(const int4*)&B[(size_t)(bn + row) * K + k0 + kc];
        }
        __syncthreads();
        short8v af[MI], bfr[NI];
        #pragma unroll
        for (int mi = 0; mi < MI; mi++)
            af[mi] = *(short8v*)&As[(wr * (BM / 2) + mi * 16 + lr) * 40 + lk * 8];
        #pragma unroll
        for (int ni = 0; ni < NI; ni++)
            bfr[ni] = *(short8v*)&Bs[(wc * (BN / 2) + ni * 16 + lr) * 40 + lk * 8];
        #pragma unroll
        for (int mi = 0; mi < MI; mi++)
            #pragma unroll
            for (int ni = 0; ni < NI; ni++)
                acc[mi][ni] = __builtin_amdgcn_mfma_f32_16x16x32_bf16(
                    af[mi], bfr[ni], acc[mi][ni], 0, 0, 0);
        __syncthreads();
    }

    #pragma unroll
    for (int mi = 0; mi < MI; mi++) {
        #pragma unroll
        for (int ni = 0; ni < NI; ni++) {
            int col = bn + wc * (BN / 2) + ni * 16 + lr;
            float bv = bias ? bias[col] : 0.f;
            #pragma unroll
            for (int j = 0; j < 4; j++) {
                int row = bm + wr * (BM / 2) + mi * 16 + lk * 4 + j;
                float v = acc[mi][ni][j] + bv;
                if (rowbias) v += rowbias[(size_t)(row % LTOK) * N + col];
                if (act == 1) v = (v > 20.f) ? v : logf(1.f + __expf(v));
                if (mode == 0) {
                    Cf[(size_t)row * N + col] = v;
                } else if (mode == 1) {
                    Cbf[(size_t)row * N + col] = f2bf(v);
                } else {
                    Cf[(size_t)row * N + col] = v;
                    if (col < 32)
                        Cbf[(size_t)row * 32 + col] = (col < DTRANK) ? f2bf(v) : (ushort)0;
                }
            }
        }
    }
}

// ---------------- im2col for patch embed (writes bf16) ----------------
__global__ void im2col_kernel(const float* __restrict__ x, ushort* __restrict__ col)
{
    int idx = blockIdx.x * 256 + threadIdx.x;        // over NTOK*768
    if (idx >= NTOK * 768) return;
    int k = idx % 768;
    int m = idx / 768;
    int b = m / LTOK, l = m % LTOK;
    int ph = l / 14, pw = l % 14;
    int c = k / 256, rr = k % 256;
    int i = rr / 16, j = rr % 16;
    col[idx] = f2bf(x[(((size_t)b * 3 + c) * 224 + ph * 16 + i) * 224 + pw * 16 + j]);
}

// ---------------- fused residual-add + LayerNorm (fp32 + bf16 outputs) -------
__global__ __launch_bounds__(64) void add_ln_kernel(
    float* __restrict__ residual, const float* __restrict__ hidden,
    const float* __restrict__ w, const float* __restrict__ b,
    float* __restrict__ xln, ushort* __restrict__ xln_bf)
{
    const int token = blockIdx.x;
    const int lane  = threadIdx.x;
    const size_t base = (size_t)token * DMODEL;
    float v[6];
    float sum = 0.f;
    #pragma unroll
    for (int i = 0; i < 6; i++) {
        int d = lane + i * 64;
        float r = residual[base + d] + hidden[base + d];
        v[i] = r;
        sum += r;
    }
    #pragma unroll
    for (int off = 32; off > 0; off >>= 1) sum += __shfl_xor(sum, off);
    float mu = sum * (1.f / DMODEL);
    float var = 0.f;
    #pragma unroll
    for (int i = 0; i < 6; i++) { float c = v[i] - mu; var += c * c; }
    #pragma unroll
    for (int off = 32; off > 0; off >>= 1) var += __shfl_xor(var, off);
    var *= (1.f / DMODEL);
    float rstd = rsqrtf(var + EPS);
    #pragma unroll
    for (int i = 0; i < 6; i++) {
        int d = lane + i * 64;
        residual[base + d] = v[i];
        float o = (v[i] - mu) * rstd * w[d] + b[d];
        xln[base + d]    = o;
        xln_bf[base + d] = f2bf(o);
    }
}

// ---------------- depthwise causal conv (k=4) + SiLU (vectorized bf16x8) -----
// One thread = 8 consecutive channels of one token. 16B loads/stores (G13).
__global__ __launch_bounds__(256) void conv_silu_kernel(
    const ushort* __restrict__ xz,     // [NTOK,1536] bf16; xc = cols 0..767
    const float* __restrict__ cw,      // [768,4]
    const float* __restrict__ cb,      // [768]
    float* __restrict__ out,           // [NTOK,768] fp32 (scan u)
    ushort* __restrict__ out_bf)       // [NTOK,768] bf16 (x-proj A)
{
    int idx = blockIdx.x * 256 + threadIdx.x;     // over NTOK * 96
    if (idx >= NTOK * (DINNER / 8)) return;
    const int eg = idx % (DINNER / 8);
    const int m  = idx / (DINNER / 8);
    const int e0 = eg * 8;
    const int b = m / LTOK, tpos = m % LTOK;

    float acc[8];
    #pragma unroll
    for (int j = 0; j < 8; j++) acc[j] = cb[e0 + j];

    #pragma unroll
    for (int tau = 0; tau < DCONV; tau++) {
        int l = tpos - (DCONV - 1) + tau;
        if (l >= 0) {
            short8v v = *(const short8v*)&xz[(size_t)(b * LTOK + l) * (2 * DINNER) + e0];
            #pragma unroll
            for (int j = 0; j < 8; j++)
                acc[j] += cw[(e0 + j) * 4 + tau] * bf2f((ushort)v[j]);
        }
    }

    float of[8];
    short8v ob;
    #pragma unroll
    for (int j = 0; j < 8; j++) {
        float s = acc[j] / (1.f + __expf(-acc[j]));
        of[j] = s;
        ob[j] = (short)f2bf(s);
    }
    const size_t base = (size_t)m * DINNER + e0;
    *(float4*)&out[base]     = *(float4*)&of[0];
    *(float4*)&out[base + 4] = *(float4*)&of[4];
    *(short8v*)&out_bf[base] = ob;
}

// ---------------- chunked parallel selective scan ----------------------------
// Grid: (BB, DINNER/SCH). Block: (SCH channels, NCH chunks) = 448 threads.
// Phase A: per-chunk local scan from h=0; record S=sum(dt), h_loc[16] -> LDS.
// Phase B: fold preceding chunks' (S, h_loc) -> true h_in (exp(S*A) composition).
// Phase C: re-run own chunk from h_in (re-reading delta/u from L2); emit y.
// NOTE: no runtime-indexed private arrays -> no scratch (r7 lesson: 290MB spill).
__global__ __launch_bounds__(SCH * NCH) void scan_chunked_kernel(
    const float* __restrict__ delta,   // [NTOK,768]
    const float* __restrict__ u,       // [NTOK,768]
    const float* __restrict__ proj,    // [NTOK,64]  (dt|B|C, padded)
    const ushort* __restrict__ xz,     // [NTOK,1536] bf16 (z = cols 768..1535)
    const float* __restrict__ A_log,   // [768,16]
    const float* __restrict__ Dp,      // [768]
    ushort* __restrict__ y)            // [NTOK,768] bf16
{
    __shared__ float S_l[NCH][SCH];
    __shared__ float hl[NCH][DSTATE][SCH];   // [chunk][state][channel]
    const int b  = blockIdx.x;
    const int dl = threadIdx.x;             // 0..SCH-1
    const int c  = threadIdx.y;             // 0..NCH-1
    const int d  = blockIdx.y * SCH + dl;

    float Arow[DSTATE];
    #pragma unroll
    for (int n = 0; n < DSTATE; n++) Arow[n] = -__expf(A_log[(size_t)d * DSTATE + n]);

    const size_t row0 = (size_t)b * LTOK + c * CL;
    float h[DSTATE];
    #pragma unroll
    for (int n = 0; n < DSTATE; n++) h[n] = 0.f;
    float S = 0.f;

    // ---- Phase A: local scan, h_in = 0 ----
    for (int i = 0; i < CL; i++) {
        const size_t row = row0 + i;
        const float dt = delta[row * DINNER + d];
        const float ut = u[row * DINNER + d];
        S += dt;
        const float du = dt * ut;
        const float4* prB = (const float4*)(proj + row * PROJW + DTRANK);
        #pragma unroll
        for (int q = 0; q < 4; q++) {
            float4 b4 = prB[q];
            h[q*4+0] = __expf(dt * Arow[q*4+0]) * h[q*4+0] + du * b4.x;
            h[q*4+1] = __expf(dt * Arow[q*4+1]) * h[q*4+1] + du * b4.y;
            h[q*4+2] = __expf(dt * Arow[q*4+2]) * h[q*4+2] + du * b4.z;
            h[q*4+3] = __expf(dt * Arow[q*4+3]) * h[q*4+3] + du * b4.w;
        }
    }
    S_l[c][dl] = S;
    #pragma unroll
    for (int n = 0; n < DSTATE; n++) hl[c][n][dl] = h[n];
    __syncthreads();

    // ---- Phase B: fold preceding chunks ----
    float hin[DSTATE];
    #pragma unroll
    for (int n = 0; n < DSTATE; n++) hin[n] = 0.f;
    for (int cp = 0; cp < c; cp++) {
        const float Sp = S_l[cp][dl];
        #pragma unroll
        for (int n = 0; n < DSTATE; n++)
            hin[n] = __expf(Sp * Arow[n]) * hin[n] + hl[cp][n][dl];
    }

    // ---- Phase C: re-run own chunk from true h_in (delta/u re-read, L2-hot) --
    const float ddp = Dp[d];
    for (int i = 0; i < CL; i++) {
        const size_t row = row0 + i;
        const float dt = delta[row * DINNER + d];
        const float ut = u[row * DINNER + d];
        const float du = dt * ut;
        const float4* prB = (const float4*)(proj + row * PROJW + DTRANK);
        const float4* prC = (const float4*)(proj + row * PROJW + DTRANK + DSTATE);
        float acc = 0.f;
        #pragma unroll
        for (int q = 0; q < 4; q++) {
            float4 b4 = prB[q];
            float4 c4 = prC[q];
            hin[q*4+0] = __expf(dt * Arow[q*4+0]) * hin[q*4+0] + du * b4.x;
            hin[q*4+1] = __expf(dt * Arow[q*4+1]) * hin[q*4+1] + du * b4.y;
            hin[q*4+2] = __expf(dt * Arow[q*4+2]) * hin[q*4+2] + du * b4.z;
            hin[q*4+3] = __expf(dt * Arow[q*4+3]) * hin[q*4+3] + du * b4.w;
            acc += hin[q*4+0] * c4.x + hin[q*4+1] * c4.y +
                   hin[q*4+2] * c4.z + hin[q*4+3] * c4.w;
        }
        float zz = bf2f(xz[row * (2 * DINNER) + DINNER + d]);
        float g  = zz / (1.f + __expf(-zz));
        y[row * DINNER + d] = f2bf((acc + ut * ddp) * g);
    }
}

// ---------------- mean pool over tokens ----------------
__global__ __launch_bounds__(256) void pool_kernel(const float* __restrict__ xln,
                                                   float* __restrict__ pooled)
{
    int idx = blockIdx.x * 256 + threadIdx.x;   // 32*384
    if (idx >= BB * DMODEL) return;
    int b = idx / DMODEL, d = idx % DMODEL;
    float s = 0.f;
    for (int l = 0; l < LTOK; l++) s += xln[((size_t)b * LTOK + l) * DMODEL + d];
    pooled[idx] = s * (1.f / LTOK);
}

// ---------------- classifier head ----------------
__global__ __launch_bounds__(256) void head_kernel(const float* __restrict__ pooled,
                                                   const float* __restrict__ hw,
                                                   const float* __restrict__ hb,
                                                   float* __restrict__ out)
{
    int idx = blockIdx.x * 256 + threadIdx.x;   // 32*1000
    if (idx >= BB * NCLS) return;
    int b = idx / NCLS, n = idx % NCLS;
    float s = hb[n];
    const float* p = pooled + (size_t)b * DMODEL;
    const float* w = hw + (size_t)n * DMODEL;
    for (int k = 0; k < DMODEL; k++) s += p[k] * w[k];
    out[idx] = s;
}

// ---------------- launcher ----------------
extern "C" void kernel_launch(void* const* d_in, const int* in_sizes, int n_in,
                              void* d_out, int out_size, void* d_ws, size_t ws_size,
                              hipStream_t stream)
{
    const float* x       = (const float*)d_in[0];
    const float* patch_w = (const float*)d_in[1];
    const float* patch_b = (const float*)d_in[2];
    const float* pos     = (const float*)d_in[3];
    const float* W_in    = (const float*)d_in[4];
    const float* conv_w  = (const float*)d_in[5];
    const float* conv_b  = (const float*)d_in[6];
    const float* W_xp    = (const float*)d_in[7];
    const float* W_dt    = (const float*)d_in[8];
    const float* b_dt    = (const float*)d_in[9];
    const float* A_log   = (const float*)d_in[10];
    const float* D_p     = (const float*)d_in[11];
    const float* W_out   = (const float*)d_in[12];
    const float* ln_w    = (const float*)d_in[13];
    const float* ln_b    = (const float*)d_in[14];
    const float* normf_w = (const float*)d_in[15];
    const float* normf_b = (const float*)d_in[16];
    const float* head_w  = (const float*)d_in[17];
    const float* head_b  = (const float*)d_in[18];
    float* out = (float*)d_out;

    // ---- fp32 workspace ----
    float* wsf = (float*)d_ws;
    size_t off = 0;
    float* xcv    = wsf + off; off += (size_t)NTOK * DINNER;
    float* proj   = wsf + off; off += (size_t)NTOK * PROJW;
    float* delta  = wsf + off; off += (size_t)NTOK * DINNER;
    float* resid  = wsf + off; off += (size_t)NTOK * DMODEL;
    float* hid    = wsf + off; off += (size_t)NTOK * DMODEL;
    float* xln    = wsf + off; off += (size_t)NTOK * DMODEL;
    float* pooled = wsf + off; off += (size_t)BB * DMODEL;
    // ---- bf16 workspace ----
    ushort* wsu = (ushort*)(wsf + off);
    size_t uoff = 0;
    ushort* Win_bf    = wsu + uoff; uoff += (size_t)24 * 1536 * DMODEL;
    ushort* Wout_bf   = wsu + uoff; uoff += (size_t)24 * DMODEL * DINNER;
    ushort* patchw_bf = wsu + uoff; uoff += (size_t)DMODEL * 768;
    ushort* Wxp_bf    = wsu + uoff; uoff += (size_t)24 * 64 * DINNER;
    ushort* Wdt_bf    = wsu + uoff; uoff += (size_t)24 * DINNER * 32;
    ushort* xln_bf    = wsu + uoff; uoff += (size_t)NTOK * DMODEL;
    ushort* xz_bf     = wsu + uoff; uoff += (size_t)NTOK * 1536;
    ushort* xcv_bf    = wsu + uoff; uoff += (size_t)NTOK * DINNER;
    ushort* dtpad_bf  = wsu + uoff; uoff += (size_t)NTOK * 32;
    ushort* y_bf      = wsu + uoff; uoff += (size_t)NTOK * DINNER;
    ushort* col_bf    = y_bf;   // patch GEMM consumes before scan ever writes

    // ---- weight casts / pads (graph-safe, every call) ----
    cast_bf16_kernel<<<2048, 256, 0, stream>>>(W_in,    Win_bf,    24 * 1536 * DMODEL / 4);
    cast_bf16_kernel<<<2048, 256, 0, stream>>>(W_out,   Wout_bf,   24 * DMODEL * DINNER / 4);
    cast_bf16_kernel<<<256,  256, 0, stream>>>(patch_w, patchw_bf, DMODEL * 768 / 4);
    pad_wxp_kernel<<<(24 * 64 * 768 + 255) / 256, 256, 0, stream>>>(W_xp, Wxp_bf);
    pad_wdt_kernel<<<(24 * 768 * 32 + 255) / 256, 256, 0, stream>>>(W_dt, Wdt_bf);

    hipMemsetAsync(resid, 0, (size_t)NTOK * DMODEL * sizeof(float), stream);

    // patch embed: im2col(bf16) + MFMA GEMM (bias + pos fused)
    im2col_kernel<<<(NTOK * 768 + 255) / 256, 256, 0, stream>>>(x, col_bf);
    gemm_mfma<128,128><<<dim3(NTOK / 128, DMODEL / 128), 256, 0, stream>>>(
        col_bf, patchw_bf, hid, nullptr, DMODEL, 768, patch_b, pos, 0, 0);

    for (int l = 0; l < 24; l++) {
        add_ln_kernel<<<NTOK, 64, 0, stream>>>(resid, hid,
                                               ln_w + (size_t)l * DMODEL,
                                               ln_b + (size_t)l * DMODEL, xln, xln_bf);
        // in-projection -> xz bf16: [6272,384] x [1536,384]^T
        gemm_mfma<128,128><<<dim3(NTOK / 128, 1536 / 128), 256, 0, stream>>>(
            xln_bf, Win_bf + (size_t)l * 1536 * DMODEL, nullptr, xz_bf,
            1536, DMODEL, nullptr, nullptr, 0, 1);
        // depthwise conv + silu (vectorized: 8 ch/thread)
        conv_silu_kernel<<<(NTOK * (DINNER / 8) + 255) / 256, 256, 0, stream>>>(
            xz_bf, conv_w + (size_t)l * DINNER * DCONV, conv_b + (size_t)l * DINNER,
            xcv, xcv_bf);
        // x-proj -> proj fp32 [6272,64] + dtpad bf16 [6272,32]
        gemm_mfma<64,64><<<dim3(NTOK / 64, 1), 256, 0, stream>>>(
            xcv_bf, Wxp_bf + (size_t)l * 64 * DINNER, proj, dtpad_bf,
            64, DINNER, nullptr, nullptr, 0, 2);
        // dt-proj + softplus -> delta fp32: [6272,32] x [768,32]^T
        gemm_mfma<128,128><<<dim3(NTOK / 128, DINNER / 128), 256, 0, stream>>>(
            dtpad_bf, Wdt_bf + (size_t)l * DINNER * 32, delta, nullptr,
            DINNER, 32, b_dt + (size_t)l * DINNER, nullptr, 1, 0);
        // chunked parallel scan (448-thread blocks, no scratch)
        scan_chunked_kernel<<<dim3(BB, DINNER / SCH), dim3(SCH, NCH), 0, stream>>>(
            delta, xcv, proj, xz_bf,
            A_log + (size_t)l * DINNER * DSTATE, D_p + (size_t)l * DINNER, y_bf);
        // out-projection: [6272,768] x [384,768]^T -> hid fp32
        gemm_mfma<128,128><<<dim3(NTOK / 128, DMODEL / 128), 256, 0, stream>>>(
            y_bf, Wout_bf + (size_t)l * DMODEL * DINNER, hid, nullptr,
            DMODEL, DINNER, nullptr, nullptr, 0, 0);
    }

    add_ln_kernel<<<NTOK, 64, 0, stream>>>(resid, hid, normf_w, normf_b, xln, xln_bf);
    pool_kernel<<<(BB * DMODEL + 255) / 256, 256, 0, stream>>>(xln, pooled);
    head_kernel<<<(BB * NCLS + 255) / 256, 256, 0, stream>>>(pooled, head_w, head_b, out);
}